// Round 1
// 1169.010 us; speedup vs baseline: 1.0839x; 1.0839x over previous
//
#include <hip/hip_runtime.h>

constexpr int Nn = 100000;
constexpr int Ne = 1600000;
constexpr float BN_EPS = 1e-5f;

constexpr int SCAN_TILE = 1024;                          // elements per block
constexpr int SCAN_NB = (Nn + SCAN_TILE - 1) / SCAN_TILE; // 98

constexpr float FIX_SCALE = 16777216.f;       // 2^24
constexpr float FIX_INV = 1.f / 16777216.f;

// ---------- small utility kernels ----------

__global__ void fill_kernel(float* __restrict__ p, float v, int n) {
  int i = blockIdx.x * blockDim.x + threadIdx.x;
  if (i < n) p[i] = v;
}

__global__ void izero_kernel(int* __restrict__ p, int n) {
  int i = blockIdx.x * blockDim.x + threadIdx.x;
  if (i < n) p[i] = 0;
}

// fused: one u64 atomic per edge packs {cnt:1 << 40 | fix24(w)}
__global__ __launch_bounds__(256)
void deg_pack_kernel(const int* __restrict__ row, const float* __restrict__ w,
                     unsigned long long* __restrict__ pk) {
  int e = (blockIdx.x * blockDim.x + threadIdx.x) * 4;
  if (e + 4 <= Ne) {
    int4 r4 = *(const int4*)(row + e);
    float4 w4 = *(const float4*)(w + e);
    atomicAdd(&pk[r4.x], (1ULL << 40) | (unsigned long long)__float2uint_rn(w4.x * FIX_SCALE));
    atomicAdd(&pk[r4.y], (1ULL << 40) | (unsigned long long)__float2uint_rn(w4.y * FIX_SCALE));
    atomicAdd(&pk[r4.z], (1ULL << 40) | (unsigned long long)__float2uint_rn(w4.z * FIX_SCALE));
    atomicAdd(&pk[r4.w], (1ULL << 40) | (unsigned long long)__float2uint_rn(w4.w * FIX_SCALE));
  } else {
    for (int i = e; i < Ne; i++) {
      atomicAdd(&pk[row[i]], (1ULL << 40) | (unsigned long long)__float2uint_rn(w[i] * FIX_SCALE));
    }
  }
}

// unpack: cnt = pk>>40 ; deg = fix*2^-24 + 1 (self loop) ; dinv = rsqrt(deg)
__global__ void dinv_cnt_kernel(const unsigned long long* __restrict__ pk,
                                float* __restrict__ dinv, int* __restrict__ cnt) {
  int i = blockIdx.x * blockDim.x + threadIdx.x;
  if (i < Nn) {
    unsigned long long v = pk[i];
    cnt[i] = (int)(v >> 40);
    float deg = (float)(v & ((1ULL << 40) - 1)) * FIX_INV + 1.0f;  // + self-loop weight
    dinv[i] = (deg > 0.f) ? rsqrtf(fmaxf(deg, 1e-12f)) : 0.f;
  }
}

// ---------- multi-block exclusive scan (cnt[Nn] -> rowptr[Nn+1], off) ----------

__global__ __launch_bounds__(256)
void scan_phase1(const int* __restrict__ cnt, int* __restrict__ bsum) {
  __shared__ int s[256];
  int b = blockIdx.x, tid = threadIdx.x;
  int base = b * SCAN_TILE + tid * 4;
  int t = 0;
#pragma unroll
  for (int i = 0; i < 4; i++) {
    int idx = base + i;
    if (idx < Nn) t += cnt[idx];
  }
  s[tid] = t;
  __syncthreads();
  for (int st = 128; st > 0; st >>= 1) {
    if (tid < st) s[tid] += s[tid + st];
    __syncthreads();
  }
  if (tid == 0) bsum[b] = s[0];
}

__global__ __launch_bounds__(128)
void scan_phase2(int* __restrict__ bsum) {  // in-place exclusive scan, SCAN_NB <= 128
  __shared__ int s[128];
  int tid = threadIdx.x;
  int v = (tid < SCAN_NB) ? bsum[tid] : 0;
  s[tid] = v;
  __syncthreads();
  for (int st = 1; st < 128; st <<= 1) {
    int u = (tid >= st) ? s[tid - st] : 0;
    __syncthreads();
    s[tid] += u;
    __syncthreads();
  }
  if (tid < SCAN_NB) bsum[tid] = s[tid] - v;  // exclusive prefix
}

__global__ __launch_bounds__(256)
void scan_phase3(const int* __restrict__ cnt, const int* __restrict__ bsum,
                 int* __restrict__ rowptr, int* __restrict__ off) {
  __shared__ int s[256];
  int b = blockIdx.x, tid = threadIdx.x;
  int base = b * SCAN_TILE + tid * 4;
  int vals[4];
  int t = 0;
#pragma unroll
  for (int i = 0; i < 4; i++) {
    int idx = base + i;
    vals[i] = (idx < Nn) ? cnt[idx] : 0;
    t += vals[i];
  }
  s[tid] = t;
  __syncthreads();
  for (int st = 1; st < 256; st <<= 1) {
    int u = (tid >= st) ? s[tid - st] : 0;
    __syncthreads();
    s[tid] += u;
    __syncthreads();
  }
  int run = bsum[b] + s[tid] - t;  // exclusive prefix for this thread's 4 elems
#pragma unroll
  for (int i = 0; i < 4; i++) {
    int idx = base + i;
    if (idx < Nn) { rowptr[idx] = run; off[idx] = run; run += vals[i]; }
  }
  if (b == SCAN_NB - 1 && tid == 255) rowptr[Nn] = bsum[b] + s[255];
}

// CSR fill: interleaved {col, norm} -> single 8B scattered store per edge
__global__ __launch_bounds__(256)
void csr_fill_kernel(const int* __restrict__ row, const int* __restrict__ col,
                     const float* __restrict__ w, const float* __restrict__ dinv,
                     int* __restrict__ off, int2* __restrict__ edge_s) {
  int e = (blockIdx.x * blockDim.x + threadIdx.x) * 4;
  if (e + 4 <= Ne) {
    int4 r4 = *(const int4*)(row + e);
    int4 c4 = *(const int4*)(col + e);
    float4 w4 = *(const float4*)(w + e);
    {
      int p = atomicAdd(&off[r4.x], 1);
      edge_s[p] = make_int2(c4.x, __float_as_int(dinv[r4.x] * w4.x * dinv[c4.x]));
    }
    {
      int p = atomicAdd(&off[r4.y], 1);
      edge_s[p] = make_int2(c4.y, __float_as_int(dinv[r4.y] * w4.y * dinv[c4.y]));
    }
    {
      int p = atomicAdd(&off[r4.z], 1);
      edge_s[p] = make_int2(c4.z, __float_as_int(dinv[r4.z] * w4.z * dinv[c4.z]));
    }
    {
      int p = atomicAdd(&off[r4.w], 1);
      edge_s[p] = make_int2(c4.w, __float_as_int(dinv[r4.w] * w4.w * dinv[c4.w]));
    }
  } else {
    for (int i = e; i < Ne; i++) {
      int r = row[i], c = col[i];
      int p = atomicAdd(&off[r], 1);
      edge_s[p] = make_int2(c, __float_as_int(dinv[r] * w[i] * dinv[c]));
    }
  }
}

// ---------- FP32 tiled GEMM: C[M,Nc] = A[M,K] @ W[K,Nc] (+bias)(relu) ----------

__global__ __launch_bounds__(256)
void gemm_kernel(const float* __restrict__ A, const float* __restrict__ W,
                 const float* __restrict__ bias, float* __restrict__ C,
                 int M, int K, int Nc, int relu) {
  constexpr int BM = 64, BN = 64, BK = 16;
  __shared__ float As[BK][BM + 4];
  __shared__ float Ws[BK][BN];
  int t = threadIdx.x;
  int tx = t & 15, ty = t >> 4;
  int row0 = blockIdx.y * BM, col0 = blockIdx.x * BN;
  float acc[4][4] = {};
  for (int k0 = 0; k0 < K; k0 += BK) {
    {
      int r = t >> 2;
      int kq = (t & 3) << 2;
      int grow = row0 + r;
      float4 a = make_float4(0.f, 0.f, 0.f, 0.f);
      if (grow < M) a = *(const float4*)(A + (size_t)grow * K + (k0 + kq));
      As[kq + 0][r] = a.x; As[kq + 1][r] = a.y;
      As[kq + 2][r] = a.z; As[kq + 3][r] = a.w;
    }
    {
      int r = t >> 4;
      int c = (t & 15) << 2;
      int gc = col0 + c;
      float4 w4 = make_float4(0.f, 0.f, 0.f, 0.f);
      if (gc < Nc) w4 = *(const float4*)(W + (size_t)(k0 + r) * Nc + gc);
      Ws[r][c + 0] = w4.x; Ws[r][c + 1] = w4.y;
      Ws[r][c + 2] = w4.z; Ws[r][c + 3] = w4.w;
    }
    __syncthreads();
#pragma unroll
    for (int kk = 0; kk < BK; kk++) {
      float4 av = *(const float4*)&As[kk][ty << 2];
      float4 wv = *(const float4*)&Ws[kk][tx << 2];
      float a4[4] = {av.x, av.y, av.z, av.w};
      float w4[4] = {wv.x, wv.y, wv.z, wv.w};
#pragma unroll
      for (int i = 0; i < 4; i++)
#pragma unroll
        for (int j = 0; j < 4; j++)
          acc[i][j] += a4[i] * w4[j];
    }
    __syncthreads();
  }
#pragma unroll
  for (int i = 0; i < 4; i++) {
    int grow = row0 + (ty << 2) + i;
    if (grow >= M) continue;
#pragma unroll
    for (int j = 0; j < 4; j++) {
      int gc = col0 + (tx << 2) + j;
      if (gc >= Nc) continue;
      float v = acc[i][j];
      if (bias) v += bias[gc];
      if (relu) v = fmaxf(v, 0.f);
      C[(size_t)grow * Nc + gc] = v;
    }
  }
}

// ---------- gather SpMM: one wave per node ----------

__global__ __launch_bounds__(256)
void gather64_kernel(const float* __restrict__ t, const int* __restrict__ rowptr,
                     const int2* __restrict__ edge_s,
                     const float* __restrict__ dinv, const float* __restrict__ bias,
                     float* __restrict__ out, int relu) {
  int wave = threadIdx.x >> 6;
  int lane = threadIdx.x & 63;
  int node = blockIdx.x * 4 + wave;
  if (node >= Nn) return;
  int start = rowptr[node], end = rowptr[node + 1];
  float s = dinv[node];
  float acc = s * s * t[(size_t)node * 64 + lane];
  for (int base = start; base < end; base += 64) {
    int m = end - base; if (m > 64) m = 64;
    int cv = 0; float nv = 0.f;
    if (lane < m) {
      int2 ev = edge_s[base + lane];
      cv = ev.x; nv = __int_as_float(ev.y);
    }
    int k = 0;
    for (; k + 4 <= m; k += 4) {
      int c0 = __shfl(cv, k), c1 = __shfl(cv, k + 1);
      int c2 = __shfl(cv, k + 2), c3 = __shfl(cv, k + 3);
      float n0 = __shfl(nv, k), n1 = __shfl(nv, k + 1);
      float n2 = __shfl(nv, k + 2), n3 = __shfl(nv, k + 3);
      float t0 = t[(size_t)c0 * 64 + lane];
      float t1 = t[(size_t)c1 * 64 + lane];
      float t2 = t[(size_t)c2 * 64 + lane];
      float t3 = t[(size_t)c3 * 64 + lane];
      acc += n0 * t0; acc += n1 * t1; acc += n2 * t2; acc += n3 * t3;
    }
    for (; k < m; k++) {
      int c = __shfl(cv, k);
      float nm = __shfl(nv, k);
      acc += nm * t[(size_t)c * 64 + lane];
    }
  }
  acc += bias[lane];
  if (relu) acc = fmaxf(acc, 0.f);
  out[(size_t)node * 64 + lane] = acc;
}

__global__ __launch_bounds__(256)
void gather128_kernel(const float* __restrict__ t, const int* __restrict__ rowptr,
                      const int2* __restrict__ edge_s,
                      const float* __restrict__ dinv, const float* __restrict__ bias,
                      float* __restrict__ out, int relu) {
  int wave = threadIdx.x >> 6;
  int lane = threadIdx.x & 63;
  int node = blockIdx.x * 4 + wave;
  if (node >= Nn) return;
  int start = rowptr[node], end = rowptr[node + 1];
  float s = dinv[node];
  float2 ti = ((const float2*)(t + (size_t)node * 128))[lane];
  float ax = s * s * ti.x, ay = s * s * ti.y;
  for (int base = start; base < end; base += 64) {
    int m = end - base; if (m > 64) m = 64;
    int cv = 0; float nv = 0.f;
    if (lane < m) {
      int2 ev = edge_s[base + lane];
      cv = ev.x; nv = __int_as_float(ev.y);
    }
    int k = 0;
    for (; k + 4 <= m; k += 4) {
      int c0 = __shfl(cv, k), c1 = __shfl(cv, k + 1);
      int c2 = __shfl(cv, k + 2), c3 = __shfl(cv, k + 3);
      float n0 = __shfl(nv, k), n1 = __shfl(nv, k + 1);
      float n2 = __shfl(nv, k + 2), n3 = __shfl(nv, k + 3);
      float2 t0 = ((const float2*)(t + (size_t)c0 * 128))[lane];
      float2 t1 = ((const float2*)(t + (size_t)c1 * 128))[lane];
      float2 t2 = ((const float2*)(t + (size_t)c2 * 128))[lane];
      float2 t3 = ((const float2*)(t + (size_t)c3 * 128))[lane];
      ax += n0 * t0.x; ay += n0 * t0.y;
      ax += n1 * t1.x; ay += n1 * t1.y;
      ax += n2 * t2.x; ay += n2 * t2.y;
      ax += n3 * t3.x; ay += n3 * t3.y;
    }
    for (; k < m; k++) {
      int c = __shfl(cv, k);
      float nm = __shfl(nv, k);
      float2 tv = ((const float2*)(t + (size_t)c * 128))[lane];
      ax += nm * tv.x; ay += nm * tv.y;
    }
  }
  float2 bb = ((const float2*)bias)[lane];
  ax += bb.x; ay += bb.y;
  if (relu) { ax = fmaxf(ax, 0.f); ay = fmaxf(ay, 0.f); }
  ((float2*)(out + (size_t)node * 128))[lane] = make_float2(ax, ay);
}

// ---------- BatchNorm ----------

__global__ __launch_bounds__(256)
void bn_stats_kernel(const float* __restrict__ x, float* __restrict__ stats, int C) {
  __shared__ float ss[256], sq[256];
  int tid = threadIdx.x;
  int col = tid & (C - 1);
  int rgrp = tid / C;
  int rpb = 256 / C;
  float s = 0.f, q = 0.f;
  for (int r = blockIdx.x * rpb + rgrp; r < Nn; r += gridDim.x * rpb) {
    float v = x[(size_t)r * C + col];
    s += v; q += v * v;
  }
  ss[tid] = s; sq[tid] = q;
  __syncthreads();
  for (int st = 128; st >= C; st >>= 1) {
    if (tid < st) { ss[tid] += ss[tid + st]; sq[tid] += sq[tid + st]; }
    __syncthreads();
  }
  if (tid < C) {
    atomicAdd(&stats[tid], ss[tid]);
    atomicAdd(&stats[C + tid], sq[tid]);
  }
}

__global__ void bn_apply_kernel(float* __restrict__ x, float* __restrict__ dup,
                                const float* __restrict__ stats,
                                const float* __restrict__ g, const float* __restrict__ beta,
                                int total, int cmask, int C) {
  int i = blockIdx.x * blockDim.x + threadIdx.x;
  if (i >= total) return;
  int c = i & cmask;
  float m = stats[c] * (1.f / Nn);
  float var = stats[C + c] * (1.f / Nn) - m * m;
  float v = (x[i] - m) * rsqrtf(var + BN_EPS) * g[c] + beta[c];
  x[i] = v;
  if (dup) dup[i] = v;
}

// ---------- Student-t cluster assignment ----------

__global__ __launch_bounds__(256)
void q_kernel(const float* __restrict__ z, const float* __restrict__ centers,
              float* __restrict__ q) {
  __shared__ float cs[50 * 32];
  __shared__ float cn[50];
  int tid = threadIdx.x;
  for (int i = tid; i < 50 * 32; i += 256) cs[i] = centers[i];
  __syncthreads();
  if (tid < 50) {
    float s = 0.f;
    for (int j = 0; j < 32; j++) { float v = cs[tid * 32 + j]; s += v * v; }
    cn[tid] = s;
  }
  __syncthreads();
  int n = blockIdx.x * blockDim.x + tid;
  if (n >= Nn) return;
  float zr[32];
  float zn = 0.f;
  const float4* zp = (const float4*)(z + (size_t)n * 32);
#pragma unroll
  for (int j = 0; j < 8; j++) {
    float4 v = zp[j];
    zr[j * 4 + 0] = v.x; zr[j * 4 + 1] = v.y;
    zr[j * 4 + 2] = v.z; zr[j * 4 + 3] = v.w;
    zn += v.x * v.x + v.y * v.y + v.z * v.z + v.w * v.w;
  }
  float qv[50];
  float qs = 0.f;
  for (int k = 0; k < 50; k++) {
    float dot = 0.f;
#pragma unroll
    for (int j = 0; j < 32; j++) dot += zr[j] * cs[k * 32 + j];
    float d2 = zn + cn[k] - 2.f * dot;
    d2 = fmaxf(d2, 0.f);
    float qq = 1.f / (1.f + d2);
    qv[k] = qq; qs += qq;
  }
  float inv = 1.f / qs;
  float* qo = q + (size_t)n * 50;
  for (int k = 0; k < 50; k++) qo[k] = qv[k] * inv;
}

// ---------- launch ----------

extern "C" void kernel_launch(void* const* d_in, const int* in_sizes, int n_in,
                              void* d_out, int out_size, void* d_ws, size_t ws_size,
                              hipStream_t stream) {
  const float* x     = (const float*)d_in[0];
  const int*   ei    = (const int*)d_in[1];
  const float* ew    = (const float*)d_in[2];
  const float* W_g1  = (const float*)d_in[3];
  const float* b_g1  = (const float*)d_in[4];
  const float* W_g2  = (const float*)d_in[5];
  const float* b_g2  = (const float*)d_in[6];
  const float* W_g3  = (const float*)d_in[7];
  const float* b_g3  = (const float*)d_in[8];
  const float* W_mu  = (const float*)d_in[9];
  const float* b_mu  = (const float*)d_in[10];
  const float* W_lv  = (const float*)d_in[11];
  const float* b_lv  = (const float*)d_in[12];
  const float* g_mu  = (const float*)d_in[13];
  const float* be_mu = (const float*)d_in[14];
  const float* g_lv  = (const float*)d_in[15];
  const float* be_lv = (const float*)d_in[16];
  const float* W_d1  = (const float*)d_in[17];
  const float* b_d1  = (const float*)d_in[18];
  const float* g_d1  = (const float*)d_in[19];
  const float* be_d1 = (const float*)d_in[20];
  const float* W_d2  = (const float*)d_in[21];
  const float* b_d2  = (const float*)d_in[22];
  const float* g_d2  = (const float*)d_in[23];
  const float* be_d2 = (const float*)d_in[24];
  const float* W_d3  = (const float*)d_in[25];
  const float* b_d3  = (const float*)d_in[26];
  const float* cent  = (const float*)d_in[27];

  const int* row = ei;
  const int* col = ei + Ne;

  float* out    = (float*)d_out;
  float* out_z  = out;
  float* out_mu = out + (size_t)Nn * 32;
  float* out_lv = out + (size_t)Nn * 64;
  float* out_xr = out + (size_t)Nn * 96;   // [N,256]
  float* out_q  = out + (size_t)Nn * 352;  // [N,50]

  // workspace layout (~66 MB):
  // dinv[N] | bufB[N*128] | stats[512] | cnt[N] | rowptr[N+1] | off[N] | bsum[128] | pad | edge_s[E int2]
  // pk[N] (u64) aliases bufB (dead until first gather)
  float* ws     = (float*)d_ws;
  float* dinv   = ws;
  float* bufB   = dinv + Nn;
  float* stats  = bufB + (size_t)Nn * 128;
  int*   cnt    = (int*)(stats + 512);
  int*   rowptr = cnt + Nn;
  int*   off    = rowptr + Nn + 1;
  int*   bsum   = off + Nn;
  int2*  edge_s = (int2*)(bsum + 128 + 1);  // +1 pad keeps 8B alignment
  unsigned long long* pk = (unsigned long long*)bufB;  // aliased; dead before gather128 writes bufB
  float* st_mu = stats, *st_lv = stats + 64, *st_d1 = stats + 128, *st_d2 = stats + 256;

  // scratch in the x_recon output region (written last):
  float* bufA = out_xr;                     // [N,128]
  float* bufC = out_xr + (size_t)Nn * 128;  // [N,64]
  float* bufD = out_xr + (size_t)Nn * 192;  // [N,64]

  auto cdiv = [](long a, long b) { return (int)((a + b - 1) / b); };
  dim3 blk(256);

  // degree + histogram: single packed u64 atomic per edge
  izero_kernel<<<cdiv(2L * Nn, 256), blk, 0, stream>>>((int*)pk, 2 * Nn);
  fill_kernel<<<1, blk, 0, stream>>>(stats, 0.f, 512);
  deg_pack_kernel<<<cdiv(Ne / 4, 256), blk, 0, stream>>>(row, ew, pk);
  dinv_cnt_kernel<<<cdiv(Nn, 256), blk, 0, stream>>>(pk, dinv, cnt);

  // CSR build: multi-block scan then fill
  scan_phase1<<<SCAN_NB, blk, 0, stream>>>(cnt, bsum);
  scan_phase2<<<1, 128, 0, stream>>>(bsum);
  scan_phase3<<<SCAN_NB, blk, 0, stream>>>(cnt, bsum, rowptr, off);
  csr_fill_kernel<<<cdiv(Ne / 4, 256), blk, 0, stream>>>(row, col, ew, dinv, off, edge_s);

  int ggrid = cdiv(Nn, 4);  // one wave per node, 4 waves/block

  // GCN layer 1: 256 -> 128, relu
  gemm_kernel<<<dim3(2, cdiv(Nn, 64)), blk, 0, stream>>>(x, W_g1, nullptr, bufA, Nn, 256, 128, 0);
  gather128_kernel<<<ggrid, blk, 0, stream>>>(bufA, rowptr, edge_s, dinv, b_g1, bufB, 1);

  // GCN layer 2: 128 -> 64, relu
  gemm_kernel<<<dim3(1, cdiv(Nn, 64)), blk, 0, stream>>>(bufB, W_g2, nullptr, bufC, Nn, 128, 64, 0);
  gather64_kernel<<<ggrid, blk, 0, stream>>>(bufC, rowptr, edge_s, dinv, b_g2, bufD, 1);

  // GCN layer 3: 64 -> 64, no relu
  gemm_kernel<<<dim3(1, cdiv(Nn, 64)), blk, 0, stream>>>(bufD, W_g3, nullptr, bufA, Nn, 64, 64, 0);
  gather64_kernel<<<ggrid, blk, 0, stream>>>(bufA, rowptr, edge_s, dinv, b_g3, bufC, 0);

  // VAE heads: 64 -> 32 (+BN); z = mu
  gemm_kernel<<<dim3(1, cdiv(Nn, 64)), blk, 0, stream>>>(bufC, W_mu, b_mu, out_mu, Nn, 64, 32, 0);
  gemm_kernel<<<dim3(1, cdiv(Nn, 64)), blk, 0, stream>>>(bufC, W_lv, b_lv, out_lv, Nn, 64, 32, 0);
  bn_stats_kernel<<<256, blk, 0, stream>>>(out_mu, st_mu, 32);
  bn_apply_kernel<<<cdiv((long)Nn * 32, 256), blk, 0, stream>>>(out_mu, out_z, st_mu, g_mu, be_mu, Nn * 32, 31, 32);
  bn_stats_kernel<<<256, blk, 0, stream>>>(out_lv, st_lv, 32);
  bn_apply_kernel<<<cdiv((long)Nn * 32, 256), blk, 0, stream>>>(out_lv, nullptr, st_lv, g_lv, be_lv, Nn * 32, 31, 32);

  // decoder 32 -> 64 -> 128 -> 256
  gemm_kernel<<<dim3(1, cdiv(Nn, 64)), blk, 0, stream>>>(out_z, W_d1, b_d1, bufD, Nn, 32, 64, 1);
  bn_stats_kernel<<<256, blk, 0, stream>>>(bufD, st_d1, 64);
  bn_apply_kernel<<<cdiv((long)Nn * 64, 256), blk, 0, stream>>>(bufD, nullptr, st_d1, g_d1, be_d1, Nn * 64, 63, 64);

  gemm_kernel<<<dim3(2, cdiv(Nn, 64)), blk, 0, stream>>>(bufD, W_d2, b_d2, bufB, Nn, 64, 128, 1);
  bn_stats_kernel<<<256, blk, 0, stream>>>(bufB, st_d2, 128);
  bn_apply_kernel<<<cdiv((long)Nn * 128, 256), blk, 0, stream>>>(bufB, nullptr, st_d2, g_d2, be_d2, Nn * 128, 127, 128);

  gemm_kernel<<<dim3(4, cdiv(Nn, 64)), blk, 0, stream>>>(bufB, W_d3, b_d3, out_xr, Nn, 128, 256, 0);

  // Student-t q
  q_kernel<<<cdiv(Nn, 256), blk, 0, stream>>>(out_z, cent, out_q);
}